// Round 1
// baseline (15769.313 us; speedup 1.0000x reference)
//
#include <hip/hip_runtime.h>
#include <hip/hip_bf16.h>
#include <stdint.h>

// ---------------------------------------------------------------------------
// QLSTM: 2-layer LSTM, T=512, B=64, D=512, H=1024, fp32 in/out.
// Persistent cooperative kernel: one phase per timestep, 1 grid barrier/phase.
// Phase p computes h0_p (layer0) and h1_{p-1} (layer1) concurrently.
// Matmuls: bf16 MFMA 32x32x16, fp32 accum. All operands pre-packed into
// exact MFMA fragment order so K-loop loads are coalesced 16B/lane.
// ---------------------------------------------------------------------------

#define T_STEPS 512
#define BATCH   64
#define DIN     512
#define HID     1024
#define NBLK    256
#define NTHR    512

typedef __attribute__((ext_vector_type(8)))  short short8;   // 8 bf16 = 4 VGPR
typedef __attribute__((ext_vector_type(16))) float f32x16;   // 32x32 acc

// ---- workspace layout (bytes, all 256-aligned) ----
// packed weights: [jt(64)][P(2)][kc(K/16)][lane(64)][8] bf16
#define OFF_WHH0 ((size_t)0)          //  8 MB  K=1024
#define OFF_WIH1 ((size_t)8388608)    //  8 MB  K=1024
#define OFF_WHH1 ((size_t)16777216)   //  8 MB  K=1024
#define OFF_WIH0 ((size_t)25165824)   //  4 MB  K=512
#define OFF_XPK  ((size_t)29360128)   // 32 MB  [t][mt(2)][kc(32)][64][8]
#define OFF_H0   ((size_t)62914560)   // 2 x 128KB  [mt(2)][kc(64)][64][8]
#define OFF_H1   ((size_t)(OFF_H0 + 262144))
#define OFF_CTR  ((size_t)(OFF_H1 + 262144))

// ---------------------------------------------------------------------------
// Pack a [4H x K] fp32 weight matrix into bf16 MFMA-B fragment order.
// Virtual 32-col tile P of granule jt = gates {2P, 2P+1}, 16 cols each.
// B[k][n]: n = lane&31, k = kc*16 + (lane>>5)*8 + j.
__global__ void pack_w_kernel(const float* __restrict__ W,
                              __hip_bfloat16* __restrict__ out, int KC) {
  int idx = blockIdx.x * blockDim.x + threadIdx.x;   // (tp*KC + kc)*64 + l
  int l  = idx & 63;
  int kc = (idx >> 6) % KC;
  int tp = (idx >> 6) / KC;      // jt*2 + P
  if (tp >= 128) return;
  int P = tp & 1, jt = tp >> 1;
  int n = l & 31;
  int gate = 2 * P + (n >> 4);
  int row  = gate * HID + jt * 16 + (n & 15);
  int K  = KC * 16;
  int k0 = kc * 16 + (l >> 5) * 8;
  const float* src = W + (size_t)row * K + k0;
  __hip_bfloat16* dst = out + (size_t)idx * 8;
#pragma unroll
  for (int j = 0; j < 8; ++j) dst[j] = __float2bfloat16(src[j]);
}

// Pack inputs [T,B,D] fp32 -> bf16 MFMA-A fragment order per t.
// A[m][k]: m = mt*32 + (lane&31), k = kc*16 + (lane>>5)*8 + j.
__global__ void pack_x_kernel(const float* __restrict__ X,
                              __hip_bfloat16* __restrict__ out) {
  int idx = blockIdx.x * blockDim.x + threadIdx.x;   // ((t*2+mt)*32+kc)*64+l
  int l  = idx & 63;
  int kc = (idx >> 6) & 31;
  int mt = (idx >> 11) & 1;
  int t  = idx >> 12;
  if (t >= T_STEPS) return;
  int m  = mt * 32 + (l & 31);
  int d0 = kc * 16 + (l >> 5) * 8;
  const float* src = X + ((size_t)t * BATCH + m) * DIN + d0;
  __hip_bfloat16* dst = out + (size_t)idx * 8;
#pragma unroll
  for (int j = 0; j < 8; ++j) dst[j] = __float2bfloat16(src[j]);
}

__device__ __forceinline__ float sigf(float x) {
  return 1.0f / (1.0f + __expf(-x));
}

// ---------------------------------------------------------------------------
__launch_bounds__(NTHR, 2)
__global__ void lstm_persist(const __hip_bfloat16* __restrict__ whh0,
                             const __hip_bfloat16* __restrict__ wih1,
                             const __hip_bfloat16* __restrict__ whh1,
                             const __hip_bfloat16* __restrict__ wih0,
                             const __hip_bfloat16* __restrict__ xpk,
                             __hip_bfloat16* h0pk, __hip_bfloat16* h1pk,
                             const float* __restrict__ bih0, const float* __restrict__ bhh0,
                             const float* __restrict__ bih1, const float* __restrict__ bhh1,
                             float* __restrict__ out, unsigned* ctr) {
  // 8 wave-partials x 2 tiles x 32 rows x 32 cols fp32 = 64 KiB
  __shared__ float dump[8][2][32][32];

  const int tid = threadIdx.x;
  const int w   = tid >> 6;        // wave 0..7  (K-split)
  const int l   = tid & 63;        // lane
  const int cu  = blockIdx.x;
  const bool L1cu = (cu >= 128);   // layer-1 CU
  const int q  = L1cu ? cu - 128 : cu;
  const int jt = q >> 1;           // 16-hidden-col granule 0..63
  const int mh = q & 1;            // 32-row half of batch

  // elementwise identity: thread <-> (row in granule, hidden col in granule)
  const int erow = tid >> 4;           // 0..31
  const int ehc  = tid & 15;           // 0..15
  const int ecol = jt * 16 + ehc;      // hidden col 0..1023
  const int em   = mh * 32 + erow;     // batch row 0..63

  // biases (i,f,g,o) for this thread's column
  float bi, bf, bg, bo;
  {
    const float* ba = L1cu ? bih1 : bih0;
    const float* bb = L1cu ? bhh1 : bhh0;
    bi = ba[0 * HID + ecol] + bb[0 * HID + ecol];
    bf = ba[1 * HID + ecol] + bb[1 * HID + ecol];
    bg = ba[2 * HID + ecol] + bb[2 * HID + ecol];
    bo = ba[3 * HID + ecol] + bb[3 * HID + ecol];
  }
  float cst = 0.0f;   // persistent cell state for (em, ecol)

  const short8* W0  = (const short8*)whh0;  // [tp][64][64] blocks
  const short8* W1a = (const short8*)wih1;
  const short8* W1b = (const short8*)whh1;
  const short8* WX  = (const short8*)wih0;  // [tp][32][64]
  const short8* XP  = (const short8*)xpk;   // [t*2+mt][32][64]
  const short8* H0  = (const short8*)h0pk;  // 2 bufs x 8192 blocks
  const short8* H1  = (const short8*)h1pk;

  for (int p = 0; p <= T_STEPS; ++p) {
    const bool active = L1cu ? (p >= 1) : (p < T_STEPS);
    if (active) {
      const int t  = L1cu ? (p - 1) : p;
      const int pb = (p + 1) & 1;          // (p-1)&1 : h-prev parity

      f32x16 acc0, acc1;
#pragma unroll
      for (int r = 0; r < 16; ++r) { acc0[r] = 0.0f; acc1[r] = 0.0f; }

      if (!L1cu) {
        // ---- layer 0: gates = h0_{p-1} @ Whh0^T + x_p @ Wih0^T ----
        const short8* A  = H0 + (size_t)pb * 8192 + (size_t)mh * 4096;
        const short8* B0 = W0 + (size_t)(jt * 2 + 0) * 4096;
        const short8* B1 = W0 + (size_t)(jt * 2 + 1) * 4096;
#pragma unroll
        for (int kc = w; kc < 64; kc += 8) {
          short8 a  = A[kc * 64 + l];
          short8 b0 = B0[kc * 64 + l];
          short8 b1 = B1[kc * 64 + l];
          acc0 = __builtin_amdgcn_mfma_f32_32x32x16_bf16(a, b0, acc0, 0, 0, 0);
          acc1 = __builtin_amdgcn_mfma_f32_32x32x16_bf16(a, b1, acc1, 0, 0, 0);
        }
        const short8* AX = XP + ((size_t)t * 2 + mh) * 2048;
        const short8* C0 = WX + (size_t)(jt * 2 + 0) * 2048;
        const short8* C1 = WX + (size_t)(jt * 2 + 1) * 2048;
#pragma unroll
        for (int kc = w; kc < 32; kc += 8) {
          short8 a  = AX[kc * 64 + l];
          short8 b0 = C0[kc * 64 + l];
          short8 b1 = C1[kc * 64 + l];
          acc0 = __builtin_amdgcn_mfma_f32_32x32x16_bf16(a, b0, acc0, 0, 0, 0);
          acc1 = __builtin_amdgcn_mfma_f32_32x32x16_bf16(a, b1, acc1, 0, 0, 0);
        }
      } else {
        // ---- layer 1: gates = h0_{p-1} @ Wih1^T + h1_{p-2} @ Whh1^T ----
        const short8* A  = H0 + (size_t)pb * 8192 + (size_t)mh * 4096;
        const short8* B0 = W1a + (size_t)(jt * 2 + 0) * 4096;
        const short8* B1 = W1a + (size_t)(jt * 2 + 1) * 4096;
#pragma unroll
        for (int kc = w; kc < 64; kc += 8) {
          short8 a  = A[kc * 64 + l];
          short8 b0 = B0[kc * 64 + l];
          short8 b1 = B1[kc * 64 + l];
          acc0 = __builtin_amdgcn_mfma_f32_32x32x16_bf16(a, b0, acc0, 0, 0, 0);
          acc1 = __builtin_amdgcn_mfma_f32_32x32x16_bf16(a, b1, acc1, 0, 0, 0);
        }
        const short8* A2 = H1 + (size_t)(p & 1) * 8192 + (size_t)mh * 4096;
        const short8* D0 = W1b + (size_t)(jt * 2 + 0) * 4096;
        const short8* D1 = W1b + (size_t)(jt * 2 + 1) * 4096;
#pragma unroll
        for (int kc = w; kc < 64; kc += 8) {
          short8 a  = A2[kc * 64 + l];
          short8 b0 = D0[kc * 64 + l];
          short8 b1 = D1[kc * 64 + l];
          acc0 = __builtin_amdgcn_mfma_f32_32x32x16_bf16(a, b0, acc0, 0, 0, 0);
          acc1 = __builtin_amdgcn_mfma_f32_32x32x16_bf16(a, b1, acc1, 0, 0, 0);
        }
      }

      // ---- dump wave partials (C/D layout: col=lane&31, row=(r&3)+8*(r>>2)+4*(lane>>5))
      __syncthreads();
#pragma unroll
      for (int r = 0; r < 16; ++r) {
        int row = (r & 3) + 8 * (r >> 2) + 4 * (l >> 5);
        dump[w][0][row][l & 31] = acc0[r];
        dump[w][1][row][l & 31] = acc1[r];
      }
      __syncthreads();

      // ---- reduce 8 partials + LSTM cell elementwise ----
      float gi = bi, gf = bf, gg = bg, go = bo;
#pragma unroll
      for (int ww = 0; ww < 8; ++ww) {
        gi += dump[ww][0][erow][ehc];
        gf += dump[ww][0][erow][ehc + 16];
        gg += dump[ww][1][erow][ehc];
        go += dump[ww][1][erow][ehc + 16];
      }
      float si = sigf(gi), sf = sigf(gf), so = sigf(go);
      float tg = tanhf(gg);
      cst = sf * cst + si * tg;
      float h = so * tanhf(cst);
      __hip_bfloat16 hb = __float2bfloat16(h);

      // packed bf16 h write: [mt][kc16=jt][lane = erow + 32*(ehc>>3)][ehc&7]
      size_t pkoff = (((size_t)mh * 64 + jt) * 64 + (erow + 32 * (ehc >> 3))) * 8 + (ehc & 7);
      if (!L1cu) {
        h0pk[(size_t)(p & 1) * 65536 + pkoff] = hb;
        if (p == T_STEPS - 1) {   // final states h0, c0
          out[(size_t)T_STEPS * BATCH * HID + 0 * BATCH * HID + (size_t)em * HID + ecol] = h;
          out[(size_t)T_STEPS * BATCH * HID + 1 * BATCH * HID + (size_t)em * HID + ecol] = cst;
        }
      } else {
        h1pk[(size_t)((p + 1) & 1) * 65536 + pkoff] = hb;
        out[((size_t)(p - 1) * BATCH + em) * HID + ecol] = h;   // sequence output
        if (p == T_STEPS) {       // final states h1, c1
          out[(size_t)T_STEPS * BATCH * HID + 2 * BATCH * HID + (size_t)em * HID + ecol] = h;
          out[(size_t)T_STEPS * BATCH * HID + 3 * BATCH * HID + (size_t)em * HID + ecol] = cst;
        }
      }
    }

    // ---- grid barrier (monotonic counter; coop launch guarantees residency)
    __syncthreads();
    if (tid == 0) {
      __threadfence();                       // release
      atomicAdd(ctr, 1u);
      unsigned target = (unsigned)NBLK * (unsigned)(p + 1);
      while (__hip_atomic_load(ctr, __ATOMIC_RELAXED, __HIP_MEMORY_SCOPE_AGENT) < target) {
        __builtin_amdgcn_s_sleep(1);
      }
      __threadfence();                       // acquire
    }
    __syncthreads();
  }
}

// ---------------------------------------------------------------------------
extern "C" void kernel_launch(void* const* d_in, const int* in_sizes, int n_in,
                              void* d_out, int out_size, void* d_ws, size_t ws_size,
                              hipStream_t stream) {
  const float* x    = (const float*)d_in[0];
  const float* Wih0 = (const float*)d_in[1];
  const float* Whh0 = (const float*)d_in[2];
  const float* b_ih0 = (const float*)d_in[3];
  const float* b_hh0 = (const float*)d_in[4];
  const float* Wih1 = (const float*)d_in[5];
  const float* Whh1 = (const float*)d_in[6];
  const float* b_ih1 = (const float*)d_in[7];
  const float* b_hh1 = (const float*)d_in[8];
  float* out = (float*)d_out;

  char* ws = (char*)d_ws;
  __hip_bfloat16* whh0p = (__hip_bfloat16*)(ws + OFF_WHH0);
  __hip_bfloat16* wih1p = (__hip_bfloat16*)(ws + OFF_WIH1);
  __hip_bfloat16* whh1p = (__hip_bfloat16*)(ws + OFF_WHH1);
  __hip_bfloat16* wih0p = (__hip_bfloat16*)(ws + OFF_WIH0);
  __hip_bfloat16* xpkp  = (__hip_bfloat16*)(ws + OFF_XPK);
  __hip_bfloat16* h0p   = (__hip_bfloat16*)(ws + OFF_H0);
  __hip_bfloat16* h1p   = (__hip_bfloat16*)(ws + OFF_H1);
  unsigned* ctr         = (unsigned*)(ws + OFF_CTR);

  // zero h double-buffers + barrier counter (ws is poisoned 0xAA each call)
  hipMemsetAsync(ws + OFF_H0, 0, 262144 * 2 + 64, stream);

  // pack weights / inputs into MFMA fragment order (bf16)
  pack_w_kernel<<<2048, 256, 0, stream>>>(Whh0, whh0p, 64);
  pack_w_kernel<<<2048, 256, 0, stream>>>(Wih1, wih1p, 64);
  pack_w_kernel<<<2048, 256, 0, stream>>>(Whh1, whh1p, 64);
  pack_w_kernel<<<1024, 256, 0, stream>>>(Wih0, wih0p, 32);
  pack_x_kernel<<<8192, 256, 0, stream>>>(x, xpkp);

  void* args[] = { &whh0p, &wih1p, &whh1p, &wih0p, &xpkp, &h0p, &h1p,
                   (void*)&b_ih0, (void*)&b_hh0, (void*)&b_ih1, (void*)&b_hh1,
                   &out, &ctr };
  hipLaunchCooperativeKernel((const void*)lstm_persist, dim3(NBLK), dim3(NTHR),
                             args, 0, stream);
}

// Round 2
// 7780.830 us; speedup vs baseline: 2.0267x; 2.0267x over previous
//
#include <hip/hip_runtime.h>
#include <hip/hip_bf16.h>
#include <stdint.h>

// ---------------------------------------------------------------------------
// QLSTM: 2-layer LSTM, T=512, B=64, D=512, H=1024, fp32 in/out.
// R2: weights persist in VGPRs (zero weight re-fetch); h exchanged via
// sc0sc1 (agent-scope relaxed atomic) loads/stores so NO cache-invalidating
// fences are needed; barrier is a relaxed atomic counter.
// Phase p computes h0_p (layer-0 CUs) and h1_{p-1} (layer-1 CUs).
// ---------------------------------------------------------------------------

#define T_STEPS 512
#define BATCH   64
#define DIN     512
#define HID     1024
#define NBLK    256
#define NTHR    512

typedef __attribute__((ext_vector_type(8)))  short short8;   // 8 bf16
typedef __attribute__((ext_vector_type(16))) float f32x16;   // 32x32 acc

union U16 { unsigned long long u[2]; short8 v; };

// ---- workspace layout (bytes) ----
#define OFF_WIH0 ((size_t)0)          // 4 MB  bf16 [4096][512]
#define OFF_WHH0 ((size_t)4194304)    // 8 MB  bf16 [4096][1024]
#define OFF_WIH1 ((size_t)12582912)   // 8 MB
#define OFF_WHH1 ((size_t)20971520)   // 8 MB
#define OFF_XBF  ((size_t)29360128)   // 33.55 MB bf16 [512][64][512]
#define OFF_H0   ((size_t)62914560)   // 2 x 128 KB  bf16 [64][1024] per parity
#define OFF_H1   ((size_t)(OFF_H0 + 262144))
#define OFF_CTR  ((size_t)(OFF_H1 + 262144))

// ---------------------------------------------------------------------------
__global__ void cvt_bf16x4(const float4* __restrict__ in,
                           ushort4* __restrict__ out, int n4) {
  int i = blockIdx.x * blockDim.x + threadIdx.x;
  if (i >= n4) return;
  float4 v = in[i];
  __hip_bfloat16 b0 = __float2bfloat16(v.x), b1 = __float2bfloat16(v.y),
                 b2 = __float2bfloat16(v.z), b3 = __float2bfloat16(v.w);
  ushort4 o;
  o.x = *(unsigned short*)&b0; o.y = *(unsigned short*)&b1;
  o.z = *(unsigned short*)&b2; o.w = *(unsigned short*)&b3;
  out[i] = o;
}

__device__ __forceinline__ float sigf(float x) {
  return 1.0f / (1.0f + __expf(-x));
}

// ---------------------------------------------------------------------------
__launch_bounds__(NTHR, 2)
__global__ void lstm_persist(const __hip_bfloat16* __restrict__ whh0,
                             const __hip_bfloat16* __restrict__ wih0,
                             const __hip_bfloat16* __restrict__ wih1,
                             const __hip_bfloat16* __restrict__ whh1,
                             const __hip_bfloat16* __restrict__ xbf,
                             __hip_bfloat16* h0buf, __hip_bfloat16* h1buf,
                             const float* __restrict__ bih0, const float* __restrict__ bhh0,
                             const float* __restrict__ bih1, const float* __restrict__ bhh1,
                             float* __restrict__ out, unsigned* ctr) {
  __shared__ float dump[8][2][32][32];   // 64 KiB: 8 wave-partials x 2 tiles

  const int tid = threadIdx.x;
  const int w   = tid >> 6;        // wave 0..7 (K-split)
  const int l   = tid & 63;
  const int cu  = blockIdx.x;
  const bool L1cu = (cu >= 128);
  const int q  = L1cu ? (cu - 128) : cu;
  const int jt = q >> 1;           // 16-hidden-col granule
  const int mh = q & 1;            // 32-row batch half

  const int n    = l & 31;         // MFMA col (B) / row (A) within tile
  const int ksub = (l >> 5) * 8;   // A/B fragment k sub-offset
  const int m    = mh * 32 + n;    // batch row for A loads

  // elementwise identity
  const int erow = tid >> 4;           // 0..31
  const int ehc  = tid & 15;           // 0..15
  const int ecol = jt * 16 + ehc;
  const int em   = mh * 32 + erow;

  float bi, bf_, bg, bo;
  {
    const float* ba = L1cu ? bih1 : bih0;
    const float* bb = L1cu ? bhh1 : bhh0;
    bi  = ba[0 * HID + ecol] + bb[0 * HID + ecol];
    bf_ = ba[1 * HID + ecol] + bb[1 * HID + ecol];
    bg  = ba[2 * HID + ecol] + bb[2 * HID + ecol];
    bo  = ba[3 * HID + ecol] + bb[3 * HID + ecol];
  }
  float cst = 0.0f;

  // ---- one-time weight preload into registers ----
  // B-frag for (kc, lane): W[wrow][kc*16 + ksub + 0..7], contiguous 16 B.
  // tile0 -> gates {0,1} (i,f); tile1 -> gates {2,3} (g,o).
  const int wr0 = ((n >> 4) + 0) * HID + jt * 16 + (n & 15);
  const int wr1 = ((n >> 4) + 2) * HID + jt * 16 + (n & 15);

  short8 w1a[8], w1b[8];   // matmul1 (K=1024): L0=Whh0, L1=Wih1
  short8 w2a[8], w2b[8];   // matmul2: L0=Wih0 (K=512, 4 used), L1=Whh1 (K=1024)
  if (!L1cu) {
#pragma unroll
    for (int kk = 0; kk < 8; ++kk) {
      int k0 = (w + 8 * kk) * 16 + ksub;
      w1a[kk] = *(const short8*)(whh0 + (size_t)wr0 * 1024 + k0);
      w1b[kk] = *(const short8*)(whh0 + (size_t)wr1 * 1024 + k0);
    }
#pragma unroll
    for (int kk = 0; kk < 4; ++kk) {
      int k0 = (w + 8 * kk) * 16 + ksub;
      w2a[kk] = *(const short8*)(wih0 + (size_t)wr0 * 512 + k0);
      w2b[kk] = *(const short8*)(wih0 + (size_t)wr1 * 512 + k0);
    }
  } else {
#pragma unroll
    for (int kk = 0; kk < 8; ++kk) {
      int k0 = (w + 8 * kk) * 16 + ksub;
      w1a[kk] = *(const short8*)(wih1 + (size_t)wr0 * 1024 + k0);
      w1b[kk] = *(const short8*)(wih1 + (size_t)wr1 * 1024 + k0);
      w2a[kk] = *(const short8*)(whh1 + (size_t)wr0 * 1024 + k0);
      w2b[kk] = *(const short8*)(whh1 + (size_t)wr1 * 1024 + k0);
    }
  }

  for (int p = 0; p <= T_STEPS; ++p) {
    const bool active = L1cu ? (p >= 1) : (p < T_STEPS);
    if (active) {
      const int pb = (p + 1) & 1;            // parity holding h0_{p-1}
      f32x16 acc0, acc1;
#pragma unroll
      for (int r = 0; r < 16; ++r) { acc0[r] = 0.0f; acc1[r] = 0.0f; }

      // ---- matmul1: h0_{p-1} @ W1^T  (coherent L2-bypass loads) ----
      {
        const __hip_bfloat16* A1e =
            h0buf + (size_t)pb * 65536 + (size_t)m * 1024 + ksub;
        const unsigned long long* A1 = (const unsigned long long*)A1e;
        U16 a1[8];
#pragma unroll
        for (int kk = 0; kk < 8; ++kk) {
          const unsigned long long* pa = A1 + (size_t)(w + 8 * kk) * 4;
          a1[kk].u[0] = __hip_atomic_load(pa,     __ATOMIC_RELAXED, __HIP_MEMORY_SCOPE_AGENT);
          a1[kk].u[1] = __hip_atomic_load(pa + 1, __ATOMIC_RELAXED, __HIP_MEMORY_SCOPE_AGENT);
        }
#pragma unroll
        for (int kk = 0; kk < 8; ++kk) {
          acc0 = __builtin_amdgcn_mfma_f32_32x32x16_bf16(a1[kk].v, w1a[kk], acc0, 0, 0, 0);
          acc1 = __builtin_amdgcn_mfma_f32_32x32x16_bf16(a1[kk].v, w1b[kk], acc1, 0, 0, 0);
        }
      }

      // ---- matmul2 ----
      if (!L1cu) {
        // x_p @ Wih0^T : x is read-only input, normal cached loads
        const short8* A2 =
            (const short8*)(xbf + ((size_t)p * 64 + m) * 512 + ksub);
        short8 a2[4];
#pragma unroll
        for (int kk = 0; kk < 4; ++kk) a2[kk] = A2[(w + 8 * kk) * 2];
#pragma unroll
        for (int kk = 0; kk < 4; ++kk) {
          acc0 = __builtin_amdgcn_mfma_f32_32x32x16_bf16(a2[kk], w2a[kk], acc0, 0, 0, 0);
          acc1 = __builtin_amdgcn_mfma_f32_32x32x16_bf16(a2[kk], w2b[kk], acc1, 0, 0, 0);
        }
      } else {
        // h1_{p-2} @ Whh1^T : coherent loads
        const __hip_bfloat16* A2e =
            h1buf + (size_t)(p & 1) * 65536 + (size_t)m * 1024 + ksub;
        const unsigned long long* A2 = (const unsigned long long*)A2e;
        U16 a2[8];
#pragma unroll
        for (int kk = 0; kk < 8; ++kk) {
          const unsigned long long* pa = A2 + (size_t)(w + 8 * kk) * 4;
          a2[kk].u[0] = __hip_atomic_load(pa,     __ATOMIC_RELAXED, __HIP_MEMORY_SCOPE_AGENT);
          a2[kk].u[1] = __hip_atomic_load(pa + 1, __ATOMIC_RELAXED, __HIP_MEMORY_SCOPE_AGENT);
        }
#pragma unroll
        for (int kk = 0; kk < 8; ++kk) {
          acc0 = __builtin_amdgcn_mfma_f32_32x32x16_bf16(a2[kk].v, w2a[kk], acc0, 0, 0, 0);
          acc1 = __builtin_amdgcn_mfma_f32_32x32x16_bf16(a2[kk].v, w2b[kk], acc1, 0, 0, 0);
        }
      }

      // ---- dump wave partials (C/D: col=lane&31, row=(r&3)+8*(r>>2)+4*(lane>>5))
      __syncthreads();
#pragma unroll
      for (int r = 0; r < 16; ++r) {
        int row = (r & 3) + 8 * (r >> 2) + 4 * (l >> 5);
        dump[w][0][row][n] = acc0[r];
        dump[w][1][row][n] = acc1[r];
      }
      __syncthreads();

      // ---- reduce 8 partials + LSTM cell ----
      float gi = bi, gf = bf_, gg = bg, go = bo;
#pragma unroll
      for (int ww = 0; ww < 8; ++ww) {
        gi += dump[ww][0][erow][ehc];
        gf += dump[ww][0][erow][ehc + 16];
        gg += dump[ww][1][erow][ehc];
        go += dump[ww][1][erow][ehc + 16];
      }
      float si = sigf(gi), sf = sigf(gf), so = sigf(go);
      float tg = tanhf(gg);
      cst = sf * cst + si * tg;
      float h = so * tanhf(cst);

      // ---- coherent h write: pair lanes -> one 4B agent-scope store ----
      __hip_bfloat16 hbf = __float2bfloat16(h);
      unsigned hb = *(const unsigned short*)&hbf;
      unsigned pr = __shfl_xor(hb, 1);
      __hip_bfloat16* hdst = L1cu ? (h1buf + (size_t)((p + 1) & 1) * 65536)
                                  : (h0buf + (size_t)(p & 1) * 65536);
      if ((ehc & 1) == 0) {
        unsigned pv = hb | (pr << 16);
        __hip_atomic_store((unsigned*)(hdst + (size_t)em * 1024 + ecol), pv,
                           __ATOMIC_RELAXED, __HIP_MEMORY_SCOPE_AGENT);
      }

      if (!L1cu) {
        if (p == T_STEPS - 1) {   // final h0, c0
          out[(size_t)T_STEPS * BATCH * HID + 0 * BATCH * HID + (size_t)em * HID + ecol] = h;
          out[(size_t)T_STEPS * BATCH * HID + 1 * BATCH * HID + (size_t)em * HID + ecol] = cst;
        }
      } else {
        out[((size_t)(p - 1) * BATCH + em) * HID + ecol] = h;   // sequence out
        if (p == T_STEPS) {       // final h1, c1
          out[(size_t)T_STEPS * BATCH * HID + 2 * BATCH * HID + (size_t)em * HID + ecol] = h;
          out[(size_t)T_STEPS * BATCH * HID + 3 * BATCH * HID + (size_t)em * HID + ecol] = cst;
        }
      }
    }

    // ---- grid barrier: no fences, no cache invalidation ----
    // Each wave drains its own (write-through sc0sc1) stores, then block
    // barrier, then one relaxed agent atomic add + poll.
    asm volatile("s_waitcnt vmcnt(0)" ::: "memory");
    __syncthreads();
    if (tid == 0) {
      __hip_atomic_fetch_add(ctr, 1u, __ATOMIC_RELAXED, __HIP_MEMORY_SCOPE_AGENT);
      const unsigned target = (unsigned)NBLK * (unsigned)(p + 1);
      while (__hip_atomic_load(ctr, __ATOMIC_RELAXED, __HIP_MEMORY_SCOPE_AGENT) < target)
        __builtin_amdgcn_s_sleep(1);
    }
    __syncthreads();
  }
}

// ---------------------------------------------------------------------------
extern "C" void kernel_launch(void* const* d_in, const int* in_sizes, int n_in,
                              void* d_out, int out_size, void* d_ws, size_t ws_size,
                              hipStream_t stream) {
  const float* x     = (const float*)d_in[0];
  const float* Wih0  = (const float*)d_in[1];
  const float* Whh0  = (const float*)d_in[2];
  const float* b_ih0 = (const float*)d_in[3];
  const float* b_hh0 = (const float*)d_in[4];
  const float* Wih1  = (const float*)d_in[5];
  const float* Whh1  = (const float*)d_in[6];
  const float* b_ih1 = (const float*)d_in[7];
  const float* b_hh1 = (const float*)d_in[8];
  float* out = (float*)d_out;

  char* ws = (char*)d_ws;
  __hip_bfloat16* wih0p = (__hip_bfloat16*)(ws + OFF_WIH0);
  __hip_bfloat16* whh0p = (__hip_bfloat16*)(ws + OFF_WHH0);
  __hip_bfloat16* wih1p = (__hip_bfloat16*)(ws + OFF_WIH1);
  __hip_bfloat16* whh1p = (__hip_bfloat16*)(ws + OFF_WHH1);
  __hip_bfloat16* xbfp  = (__hip_bfloat16*)(ws + OFF_XBF);
  __hip_bfloat16* h0p   = (__hip_bfloat16*)(ws + OFF_H0);
  __hip_bfloat16* h1p   = (__hip_bfloat16*)(ws + OFF_H1);
  unsigned* ctr         = (unsigned*)(ws + OFF_CTR);

  // zero h double-buffers + barrier counter (ws re-poisoned each call)
  hipMemsetAsync(ws + OFF_H0, 0, 262144 * 2 + 64, stream);

  // fp32 -> bf16 plain row-major copies
  cvt_bf16x4<<<2048,  256, 0, stream>>>((const float4*)Wih0, (ushort4*)wih0p, 2097152 / 4);
  cvt_bf16x4<<<4096,  256, 0, stream>>>((const float4*)Whh0, (ushort4*)whh0p, 4194304 / 4);
  cvt_bf16x4<<<4096,  256, 0, stream>>>((const float4*)Wih1, (ushort4*)wih1p, 4194304 / 4);
  cvt_bf16x4<<<4096,  256, 0, stream>>>((const float4*)Whh1, (ushort4*)whh1p, 4194304 / 4);
  cvt_bf16x4<<<16384, 256, 0, stream>>>((const float4*)x,    (ushort4*)xbfp, 16777216 / 4);

  void* args[] = { &whh0p, &wih0p, &wih1p, &whh1p, &xbfp, &h0p, &h1p,
                   (void*)&b_ih0, (void*)&b_hh0, (void*)&b_ih1, (void*)&b_hh1,
                   &out, &ctr };
  hipLaunchCooperativeKernel((const void*)lstm_persist, dim3(NBLK), dim3(NTHR),
                             args, 0, stream);
}